// Round 9
// baseline (2274.503 us; speedup 1.0000x reference)
//
#include <hip/hip_runtime.h>
#include <hip/hip_fp16.h>

#define Tn 1024
#define NB 128

// sigmoid(x) = 1/(1+exp2(S_RZ*x)); tanh(u): e=exp2(S_N*u), n=(1-e)/(1+e)
#define S_RZ (-1.4426950408889634f)
#define S_N  (-2.8853900817779268f)

typedef _Float16 h2_t  __attribute__((ext_vector_type(2)));
typedef _Float16 f16x8 __attribute__((ext_vector_type(8)));
typedef float    f32x4 __attribute__((ext_vector_type(4)));

__device__ __forceinline__ float dot2f(h2_t a, h2_t b, float c) {
#if __has_builtin(__builtin_amdgcn_fdot2)
  return __builtin_amdgcn_fdot2(a, b, c, false);
#else
  return c + (float)a[0] * (float)b[0] + (float)a[1] * (float)b[1];
#endif
}

__device__ __forceinline__ h2_t u2h(unsigned u) {
  union { unsigned u; h2_t h; } c; c.u = u; return c.h;
}

// ---- Phase 1: packed token table, f32.
// For hidden row j (0..255): w=j>>6, tb=(j>>4)&3, c=j&15; slot = w*192 + c*12 + tb*3 + g
//   g=0: S_RZ*(gi_r+bhh_r); g=1: S_RZ*(gi_z+bhh_z); g=2: S_N*gi_n
__global__ __launch_bounds__(768)
void gv_build(const float* __restrict__ emb,
              const float* __restrict__ wihf, const float* __restrict__ bihf, const float* __restrict__ bhhf,
              const float* __restrict__ wihb, const float* __restrict__ bihb, const float* __restrict__ bhhb,
              float* __restrict__ gvp)
{
  const int d  = blockIdx.x >> 7;
  const int v4 = (blockIdx.x & 127) * 4;
  const float* wih = d ? wihb : wihf;
  const float* bih = d ? bihb : bihf;
  const float* bhh = d ? bhhb : bhhf;
  __shared__ float se[4][128];
  const int tid = threadIdx.x;
  if (tid < 512) se[tid >> 7][tid & 127] = emb[(v4 + (tid >> 7)) * 128 + (tid & 127)];
  __syncthreads();
  const int row = tid;
  const float b0 = bih[row];
  float a0 = b0, a1 = b0, a2 = b0, a3 = b0;
  #pragma unroll
  for (int e = 0; e < 128; e += 4) {
    const float4 w = *reinterpret_cast<const float4*>(&wih[row * 128 + e]);
    a0 = fmaf(w.x, se[0][e], a0); a0 = fmaf(w.y, se[0][e+1], a0);
    a0 = fmaf(w.z, se[0][e+2], a0); a0 = fmaf(w.w, se[0][e+3], a0);
    a1 = fmaf(w.x, se[1][e], a1); a1 = fmaf(w.y, se[1][e+1], a1);
    a1 = fmaf(w.z, se[1][e+2], a1); a1 = fmaf(w.w, se[1][e+3], a1);
    a2 = fmaf(w.x, se[2][e], a2); a2 = fmaf(w.y, se[2][e+1], a2);
    a2 = fmaf(w.z, se[2][e+2], a2); a2 = fmaf(w.w, se[2][e+3], a2);
    a3 = fmaf(w.x, se[3][e], a3); a3 = fmaf(w.y, se[3][e+1], a3);
    a3 = fmaf(w.z, se[3][e+2], a3); a3 = fmaf(w.w, se[3][e+3], a3);
  }
  const int g  = row >> 8, j = row & 255;
  const int w  = j >> 6, tb = (j >> 4) & 3, c = j & 15;
  const float sc  = (g == 2) ? S_N : S_RZ;
  const float add = (g < 2) ? bhh[row] : 0.f;
  const int slot = w * 192 + c * 12 + tb * 3 + g;
  float* out = gvp + (size_t)(d * 512 + v4) * 768 + slot;
  out[0]    = sc * (a0 + add);
  out[768]  = sc * (a1 + add);
  out[1536] = sc * (a2 + add);
  out[2304] = sc * (a3 + add);
}

// chain head: D = A*B + ZQv (VGPR zero quad, loop-invariant); rest: D += A*B.
// C/D share one acc_cd bit -> both must be VGPR; A=VGPR, B=AGPR (own ACC bits).
#define MFMA_Z(D, A, B) \
  asm("v_mfma_f32_16x16x32_f16 %0, %1, %2, %3" : "=&v"(D) : "v"(A), "a"(B), "v"(ZQv))
#define MFMA_A(D, A, B) \
  asm("v_mfma_f32_16x16x32_f16 %0, %1, %2, %0" : "+v"(D) : "v"(A), "a"(B))

#define ROW12(MAC, AF, ks) \
  MAC(aR0, AF, bf[0][0][ks]); MAC(aZ0, AF, bf[1][0][ks]); MAC(aN0, AF, bf[2][0][ks]); \
  MAC(aR1, AF, bf[0][1][ks]); MAC(aZ1, AF, bf[1][1][ks]); MAC(aN1, AF, bf[2][1][ks]); \
  MAC(aR2, AF, bf[0][2][ks]); MAC(aZ2, AF, bf[1][2][ks]); MAC(aN2, AF, bf[2][2][ks]); \
  MAC(aR3, AF, bf[0][3][ks]); MAC(aZ3, AF, bf[1][3][ks]); MAC(aN3, AF, bf[2][3][ks]);

#define UPD(tb, AR, AZ, AN) { \
  const float pr = gvv[3*(tb)+0] + AR[0]; \
  const float er = __builtin_amdgcn_exp2f(pr); \
  const float rr = __builtin_amdgcn_rcpf(1.f + er); \
  const float pz = gvv[3*(tb)+1] + AZ[0]; \
  const float ez = __builtin_amdgcn_exp2f(pz); \
  const float zz = __builtin_amdgcn_rcpf(1.f + ez); \
  float y = fmaf(rr, AN[0] + bn[tb], gvv[3*(tb)+2]); \
  y = fminf(y, 126.f); \
  const float en = __builtin_amdgcn_exp2f(y); \
  const float nn = (1.f - en) * __builtin_amdgcn_rcpf(1.f + en); \
  const float hnew = fmaf(zz, ho##tb - nn, nn); \
  ho##tb = hnew; \
  if (lg == 0) hls[cur ^ 1][w * 64 + (tb) * 16 + c] = (_Float16)hnew; }

// ---- Phase 2: per-(batch,dir) GRU scan via MFMA matvec, weights pinned in AGPRs.
// 256 thr = 4 waves, 1 wave/SIMD (512 unified regs/wave). Wave w owns h-rows
// w*64..w*64+63 x 3 gates = 12 tiles; B-frags = 96 f16x8 = 384 AGPRs ("a"-pinned).
// A = h replicated rows (LDS broadcast); acc in VGPR (direct VALU read).
// Lane c handles 4 h-rows (tb=0..3). One barrier/step. Emission: wave w = label w.
__global__ __launch_bounds__(256, 1)
void gru_scan(const int* __restrict__ x,
              const float* __restrict__ gvp,
              const float* __restrict__ whhf,
              const float* __restrict__ whhb,
              const float* __restrict__ bhhf,
              const float* __restrict__ bhhb,
              const float* __restrict__ fcw,
              float* __restrict__ em)
{
  const int tid = threadIdx.x;
  const int w   = tid >> 6;
  const int l   = tid & 63;
  const int c   = l & 15;
  const int lg  = l >> 4;
  const int dir = blockIdx.x & 1;
  const int b   = blockIdx.x >> 1;

  const float* whh = dir ? whhb : whhf;
  const float* bhh = dir ? bhhb : bhhf;

  __shared__ __align__(16) _Float16 hls[2][256];  // h double-buffer (1 KB)
  __shared__ float gvs[2][768];                   // staged token table (6 KB)

  if (tid < 64) reinterpret_cast<uint4*>(hls)[tid] = make_uint4(0, 0, 0, 0);

  // B-frags: bf[g][tb][ks]; lane (c,lg): W[g*256 + w*64 + tb*16 + c][ks*32 + lg*8 + e] * sc
  f16x8 bf[3][4][8];
  #pragma unroll
  for (int g = 0; g < 3; ++g) {
    const float sc = (g == 2) ? S_N : S_RZ;
    #pragma unroll
    for (int tb = 0; tb < 4; ++tb) {
      const float* wrow = whh + (size_t)(g * 256 + w * 64 + tb * 16 + c) * 256 + lg * 8;
      #pragma unroll
      for (int ks = 0; ks < 8; ++ks) {
        const float4 f0 = *reinterpret_cast<const float4*>(wrow + ks * 32);
        const float4 f1 = *reinterpret_cast<const float4*>(wrow + ks * 32 + 4);
        f16x8 v;
        v[0] = (_Float16)(f0.x * sc); v[1] = (_Float16)(f0.y * sc);
        v[2] = (_Float16)(f0.z * sc); v[3] = (_Float16)(f0.w * sc);
        v[4] = (_Float16)(f1.x * sc); v[5] = (_Float16)(f1.y * sc);
        v[6] = (_Float16)(f1.z * sc); v[7] = (_Float16)(f1.w * sc);
        bf[g][tb][ks] = v;
      }
    }
  }

  float bn[4];
  #pragma unroll
  for (int tb = 0; tb < 4; ++tb) bn[tb] = S_N * bhh[512 + w * 64 + tb * 16 + c];

  // emission fragments: wave w = label w; lane l: k-pairs l and l+64
  h2_t fce0, fce1;
  fce0[0] = (_Float16)fcw[w * 512 + dir * 256 + 2 * l];
  fce0[1] = (_Float16)fcw[w * 512 + dir * 256 + 2 * l + 1];
  fce1[0] = (_Float16)fcw[w * 512 + dir * 256 + 128 + 2 * l];
  fce1[1] = (_Float16)fcw[w * 512 + dir * 256 + 128 + 2 * l + 1];

  f32x4 ZQv = {0.f, 0.f, 0.f, 0.f};   // VGPR zero quad (C of chain heads)

  const int*   xb  = x + b * Tn;
  float*       emo = em + (size_t)(dir * NB + b) * (Tn * 4);
  const float* gvd = gvp + (size_t)dir * (512 * 768);

  // prologue: stage gv for step 0; prefetch token for step 1
  int tok1;
  {
    const int tk0 = xb[dir ? (Tn - 1) : 0];
    const float* g0 = gvd + (size_t)tk0 * 768;
    gvs[0][tid]       = g0[tid];
    gvs[0][tid + 256] = g0[tid + 256];
    gvs[0][tid + 512] = g0[tid + 512];
    tok1 = xb[dir ? (Tn - 2) : 1];
  }
  float ho0 = 0.f, ho1 = 0.f, ho2 = 0.f, ho3 = 0.f;
  __syncthreads();

  for (int t = 0; t < Tn; ++t) {
    const int cur = t & 1;

    // stage gv row for step t+1 (global loads issued early, LDS-written late)
    const float* gr = gvd + (size_t)tok1 * 768;
    const float su0 = gr[tid];
    const float su1 = gr[tid + 256];
    const float su2 = gr[tid + 512];
    {
      const int s2 = (t + 2 < Tn) ? (t + 2) : (Tn - 1);
      tok1 = xb[dir ? (Tn - 1 - s2) : s2];
    }

    // emission of h_{t-1} (hls[cur]); wave w produces label w
    if (t > 0) {
      const unsigned hw0 = *reinterpret_cast<const unsigned*>(&hls[cur][2 * l]);
      const unsigned hw1 = *reinterpret_cast<const unsigned*>(&hls[cur][2 * l + 128]);
      float pa = dot2f(fce0, u2h(hw0), 0.f);
      pa = dot2f(fce1, u2h(hw1), pa);
      pa += __shfl_xor(pa, 1);  pa += __shfl_xor(pa, 2);  pa += __shfl_xor(pa, 4);
      pa += __shfl_xor(pa, 8);  pa += __shfl_xor(pa, 16); pa += __shfl_xor(pa, 32);
      if (l == 0) emo[(size_t)(dir ? (Tn - t) : (t - 1)) * 4 + w] = pa;
    }

    // per-lane gate constants for this token (3 x b128)
    const f32x4* gq = reinterpret_cast<const f32x4*>(gvs[cur] + w * 192 + c * 12);
    const f32x4 q0 = gq[0], q1 = gq[1], q2 = gq[2];
    float gvv[12];
    gvv[0] = q0[0]; gvv[1]  = q0[1]; gvv[2]  = q0[2]; gvv[3]  = q0[3];
    gvv[4] = q1[0]; gvv[5]  = q1[1]; gvv[6]  = q1[2]; gvv[7]  = q1[3];
    gvv[8] = q2[0]; gvv[9]  = q2[1]; gvv[10] = q2[2]; gvv[11] = q2[3];

    // A-frags (h replicated): afr[ks] = hls[cur][ks*32 + lg*8 ..+7]
    const f16x8* hap = reinterpret_cast<const f16x8*>(&hls[cur][lg * 8]);
    f32x4 aR0, aZ0, aN0, aR1, aZ1, aN1, aR2, aZ2, aN2, aR3, aZ3, aN3;
    {
      const f16x8 af0 = hap[0], af1 = hap[4], af2 = hap[8], af3 = hap[12];
      ROW12(MFMA_Z, af0, 0)
      ROW12(MFMA_A, af1, 1)
      ROW12(MFMA_A, af2, 2)
      ROW12(MFMA_A, af3, 3)
    }
    {
      const f16x8 af4 = hap[16], af5 = hap[20], af6 = hap[24], af7 = hap[28];
      ROW12(MFMA_A, af4, 4)
      ROW12(MFMA_A, af5, 5)
      ROW12(MFMA_A, af6, 6)
      ROW12(MFMA_A, af7, 7)
    }
    asm volatile("s_nop 7\n\ts_nop 3");   // MFMA(v-dst) -> VALU read hazard cover
    __builtin_amdgcn_sched_barrier(0);

    // h-update: 4 rows per lane
    UPD(0, aR0, aZ0, aN0)
    UPD(1, aR1, aZ1, aN1)
    UPD(2, aR2, aZ2, aN2)
    UPD(3, aR3, aZ3, aN3)

    // write staged gv for next step
    gvs[cur ^ 1][tid]       = su0;
    gvs[cur ^ 1][tid + 256] = su1;
    gvs[cur ^ 1][tid + 512] = su2;
    __syncthreads();
  }

  // final emission: h_{Tn-1} lives in hls[0]
  {
    const unsigned hw0 = *reinterpret_cast<const unsigned*>(&hls[0][2 * l]);
    const unsigned hw1 = *reinterpret_cast<const unsigned*>(&hls[0][2 * l + 128]);
    float pa = dot2f(fce0, u2h(hw0), 0.f);
    pa = dot2f(fce1, u2h(hw1), pa);
    pa += __shfl_xor(pa, 1);  pa += __shfl_xor(pa, 2);  pa += __shfl_xor(pa, 4);
    pa += __shfl_xor(pa, 8);  pa += __shfl_xor(pa, 16); pa += __shfl_xor(pa, 32);
    if (l == 0) emo[(size_t)(dir ? 0 : (Tn - 1)) * 4 + w] = pa;
  }
}

// ---- Phase 3: CRF negative log-likelihood per batch (4 lanes per batch element)
__global__ __launch_bounds__(64)
void crf_nllh(const int* __restrict__ tags,
              const float* __restrict__ em,
              const float* __restrict__ fc_b,
              const float* __restrict__ st,
              const float* __restrict__ et,
              const float* __restrict__ tr,
              float* __restrict__ llh)
{
  const int lane = threadIdx.x;
  const int l = lane & 3;
  const int q = lane >> 2;
  const int b = blockIdx.x * 16 + q;
  const float* ef = em + (size_t)b * Tn * 4;
  const float* eb = em + ((size_t)NB + b) * Tn * 4;
  const int* tg = tags + b * Tn;
  const float fcb = fc_b[l];
  const float tc0 = tr[l * 4 + l];
  const float tc1 = tr[(l ^ 1) * 4 + l];
  const float tc2 = tr[(l ^ 2) * 4 + l];
  const float tc3 = tr[(l ^ 3) * 4 + l];

  const float e0 = ef[l] + eb[l] + fcb;
  float alpha = st[l] + e0;
  int tprev = tg[0];
  float score = (tprev == l) ? (st[l] + e0) : 0.f;

  #pragma unroll 8
  for (int t = 1; t < Tn; ++t) {
    const float e = ef[t * 4 + l] + eb[t * 4 + l] + fcb;
    const int tc = tg[t];
    if (tc == l) {
      const int s2 = tprev ^ l;
      const float tsel = (s2 & 1) ? ((s2 & 2) ? tc3 : tc1)
                                  : ((s2 & 2) ? tc2 : tc0);
      score += e + tsel;
    }
    tprev = tc;
    const float a1 = __shfl_xor(alpha, 1);
    const float a2 = __shfl_xor(alpha, 2);
    const float a3 = __shfl_xor(alpha, 3);
    const float v0 = alpha + tc0;
    const float v1 = a1 + tc1;
    const float v2 = a2 + tc2;
    const float v3 = a3 + tc3;
    const float mx = fmaxf(fmaxf(v0, v1), fmaxf(v2, v3));
    const float s = __expf(v0 - mx) + __expf(v1 - mx) + __expf(v2 - mx) + __expf(v3 - mx);
    alpha = mx + __logf(s) + e;
  }

  score += (tprev == l) ? et[l] : 0.f;
  float ae = alpha + et[l];
  float m1 = fmaxf(ae, __shfl_xor(ae, 1));
  m1 = fmaxf(m1, __shfl_xor(m1, 2));
  float se = __expf(ae - m1);
  se += __shfl_xor(se, 1);
  se += __shfl_xor(se, 2);
  const float logZ = m1 + __logf(se);
  float sc = score + __shfl_xor(score, 1);
  sc += __shfl_xor(sc, 2);
  if (l == 0) llh[b] = sc - logZ;
}

// ---- Phase 4: out = -mean(llh)
__global__ __launch_bounds__(128)
void reduce_mean(const float* __restrict__ llh, float* __restrict__ out)
{
  const int t = threadIdx.x;
  float v = llh[t];
  #pragma unroll
  for (int m = 32; m >= 1; m >>= 1) v += __shfl_xor(v, m);
  __shared__ float s2[2];
  if ((t & 63) == 0) s2[t >> 6] = v;
  __syncthreads();
  if (t == 0) out[0] = -(s2[0] + s2[1]) * (1.f / 128.f);
}

extern "C" void kernel_launch(void* const* d_in, const int* in_sizes, int n_in,
                              void* d_out, int out_size, void* d_ws, size_t ws_size,
                              hipStream_t stream) {
  const int*   x    = (const int*)d_in[0];
  const int*   tags = (const int*)d_in[1];
  // d_in[2] = mask (all ones) -- unused
  const float* emb  = (const float*)d_in[3];
  const float* wihf = (const float*)d_in[4];
  const float* whhf = (const float*)d_in[5];
  const float* bihf = (const float*)d_in[6];
  const float* bhhf = (const float*)d_in[7];
  const float* wihb = (const float*)d_in[8];
  const float* whhb = (const float*)d_in[9];
  const float* bihb = (const float*)d_in[10];
  const float* bhhb = (const float*)d_in[11];
  const float* fcw  = (const float*)d_in[12];
  const float* fcb  = (const float*)d_in[13];
  const float* st   = (const float*)d_in[14];
  const float* et   = (const float*)d_in[15];
  const float* tr   = (const float*)d_in[16];

  char* ws = (char*)d_ws;
  float* gvp = (float*)ws;                          // 2*512*768*4   = 3,145,728 B
  float* em  = (float*)(ws + 3145728);              // 2*128*1024*4*4 = 4,194,304 B
  float* llh = (float*)(ws + 3145728 + 4194304);    // 512 B

  gv_build<<<dim3(256), dim3(768), 0, stream>>>(emb, wihf, bihf, bhhf, wihb, bihb, bhhb, gvp);
  gru_scan<<<dim3(256), dim3(256), 0, stream>>>(x, gvp, whhf, whhb, bhhf, bhhb, fcw, em);
  crf_nllh<<<dim3(8), dim3(64), 0, stream>>>(tags, em, fcb, st, et, tr, llh);
  reduce_mean<<<dim3(1), dim3(128), 0, stream>>>(llh, (float*)d_out);
}